// Round 1
// baseline (1367.198 us; speedup 1.0000x reference)
//
#include <hip/hip_runtime.h>

typedef unsigned short u16;
typedef u16 u16x4 __attribute__((ext_vector_type(4)));
typedef u16 u16x8 __attribute__((ext_vector_type(8)));
typedef __bf16 bf16x8 __attribute__((ext_vector_type(8)));
typedef float f32x4 __attribute__((ext_vector_type(4)));

#define NB   2
#define NQH  32
#define NKH  8
#define SEQ  2048
#define DIM  128
#define BKV  64   // kv keys per tile
#define QT   64   // q rows per block (16 per wave)

__device__ __forceinline__ u16 f2bf(float f) {
  unsigned u = __builtin_bit_cast(unsigned, f);
  u += 0x7FFFu + ((u >> 16) & 1u);   // round-to-nearest-even
  return (u16)(u >> 16);
}

__device__ __forceinline__ f32x4 mfma16(u16x8 a, u16x8 b, f32x4 c) {
  return __builtin_amdgcn_mfma_f32_16x16x32_bf16(
      __builtin_bit_cast(bf16x8, a), __builtin_bit_cast(bf16x8, b), c, 0, 0, 0);
}

// swizzled LDS address: byte ^= (row&7)<<4  (keeps 16B granules intact)
__device__ __forceinline__ u16* lds_at(u16* base, int row, int col, int rowBytes) {
  int byte = row * rowBytes + col * 2;
  byte ^= (row & 7) << 4;
  return (u16*)((char*)base + byte);
}

__global__ __launch_bounds__(256) void gqa_fwd(
    const float* __restrict__ Qg, const float* __restrict__ Kg,
    const float* __restrict__ Vg, float* __restrict__ Og) {
  __shared__ __align__(16) u16 ldsK[BKV * DIM];    // [64][128] bf16, swizzled
  __shared__ __align__(16) u16 ldsVT[DIM * BKV];   // [128][64] bf16 (V^T), swizzled
  __shared__ __align__(16) u16 ldsP[4][16 * 72];   // per-wave P, stride 72 (pad)

  const int tid  = threadIdx.x;
  const int wave = tid >> 6;
  const int lane = tid & 63;
  const int lr   = lane & 15;   // row/col within 16
  const int lg   = lane >> 4;   // group 0..3

  const int qtile = blockIdx.x;          // 0..31
  const int bqh   = blockIdx.y;          // 0..63
  const int b     = bqh / NQH;
  const int qh    = bqh % NQH;
  const int kh    = qh / (NQH / NKH);

  const size_t qbase = (size_t)bqh * SEQ * DIM;
  const size_t kbase = (size_t)(b * NKH + kh) * SEQ * DIM;

  const int qrow0 = qtile * QT + wave * 16;
  const float scale = 0.08838834764831845f;  // 1/sqrt(128)

  // preload Q fragments (scale folded in)
  u16x8 qf[4];
  #pragma unroll
  for (int s = 0; s < 4; ++s) {
    const float* qp = Qg + qbase + (size_t)(qrow0 + lr) * DIM + 32 * s + 8 * lg;
    u16x8 v;
    #pragma unroll
    for (int e = 0; e < 8; ++e) v[e] = f2bf(qp[e] * scale);
    qf[s] = v;
  }

  const f32x4 zero4 = {0.f, 0.f, 0.f, 0.f};
  f32x4 oacc[8];
  #pragma unroll
  for (int dt = 0; dt < 8; ++dt) oacc[dt] = zero4;
  float mrow[4], lrow[4];
  #pragma unroll
  for (int e = 0; e < 4; ++e) { mrow[e] = -INFINITY; lrow[e] = 0.0f; }

  for (int kt = 0; kt < SEQ / BKV; ++kt) {
    __syncthreads();   // previous tile's LDS reads done before overwrite
    {
      // stage K tile: coalesced float4 reads, bf16 swizzled writes
      const float* src = Kg + kbase + (size_t)kt * BKV * DIM;
      #pragma unroll
      for (int u = 0; u < 8; ++u) {
        int c  = tid + 256 * u;        // 0..2047 float4-chunks
        int j  = c >> 5;               // key row 0..63
        int dm = (c & 31) * 4;         // d offset
        float4 v = *(const float4*)(src + j * DIM + dm);
        u16x4 w = { f2bf(v.x), f2bf(v.y), f2bf(v.z), f2bf(v.w) };
        *(u16x4*)lds_at(ldsK, j, dm, 2 * DIM) = w;
      }
      // stage V^T tile
      const float* vsrc = Vg + kbase + (size_t)kt * BKV * DIM;
      #pragma unroll
      for (int u = 0; u < 8; ++u) {
        int c  = tid + 256 * u;
        int j  = c >> 5;
        int dm = (c & 31) * 4;
        float4 v = *(const float4*)(vsrc + j * DIM + dm);
        *lds_at(ldsVT, dm + 0, j, 2 * BKV) = f2bf(v.x);
        *lds_at(ldsVT, dm + 1, j, 2 * BKV) = f2bf(v.y);
        *lds_at(ldsVT, dm + 2, j, 2 * BKV) = f2bf(v.z);
        *lds_at(ldsVT, dm + 3, j, 2 * BKV) = f2bf(v.w);
      }
    }
    __syncthreads();

    // S = Q K^T  (16 x 64 per wave)
    f32x4 sacc[4];
    #pragma unroll
    for (int jt = 0; jt < 4; ++jt) sacc[jt] = zero4;
    #pragma unroll
    for (int jt = 0; jt < 4; ++jt) {
      #pragma unroll
      for (int s = 0; s < 4; ++s) {
        u16x8 kf = *(const u16x8*)lds_at(ldsK, jt * 16 + lr, 32 * s + 8 * lg, 2 * DIM);
        sacc[jt] = mfma16(qf[s], kf, sacc[jt]);
      }
    }

    // online softmax (rows live across the 16-lane group; regs e=0..3)
    float corr[4];
    #pragma unroll
    for (int e = 0; e < 4; ++e) {
      float t = fmaxf(fmaxf(sacc[0][e], sacc[1][e]), fmaxf(sacc[2][e], sacc[3][e]));
      #pragma unroll
      for (int m = 1; m < 16; m <<= 1) t = fmaxf(t, __shfl_xor(t, m, 64));
      float mn = fmaxf(mrow[e], t);
      corr[e]  = __expf(mrow[e] - mn);   // exp(-inf)=0 on first tile
      mrow[e]  = mn;
    }
    float rsum[4] = {0.f, 0.f, 0.f, 0.f};
    #pragma unroll
    for (int jt = 0; jt < 4; ++jt) {
      #pragma unroll
      for (int e = 0; e < 4; ++e) {
        float p = __expf(sacc[jt][e] - mrow[e]);
        rsum[e] += p;
        ldsP[wave][(4 * lg + e) * 72 + lr + 16 * jt] = f2bf(p);
      }
    }
    #pragma unroll
    for (int e = 0; e < 4; ++e) {
      float t = rsum[e];
      #pragma unroll
      for (int m = 1; m < 16; m <<= 1) t += __shfl_xor(t, m, 64);
      lrow[e] = lrow[e] * corr[e] + t;
      #pragma unroll
      for (int dt = 0; dt < 8; ++dt) oacc[dt][e] *= corr[e];
    }

    // O += P V   (P via per-wave LDS transpose; V^T frags from LDS)
    u16x8 pf[2];
    #pragma unroll
    for (int ks = 0; ks < 2; ++ks)
      pf[ks] = *(const u16x8*)&ldsP[wave][lr * 72 + 32 * ks + 8 * lg];
    #pragma unroll
    for (int dt = 0; dt < 8; ++dt) {
      #pragma unroll
      for (int ks = 0; ks < 2; ++ks) {
        u16x8 vf = *(const u16x8*)lds_at(ldsVT, dt * 16 + lr, 32 * ks + 8 * lg, 2 * BKV);
        oacc[dt] = mfma16(pf[ks], vf, oacc[dt]);
      }
    }
  }

  // epilogue: normalize and store (f32)
  #pragma unroll
  for (int e = 0; e < 4; ++e) {
    float inv = 1.0f / lrow[e];
    int row = qrow0 + 4 * lg + e;
    float* op = Og + qbase + (size_t)row * DIM;
    #pragma unroll
    for (int dt = 0; dt < 8; ++dt) op[dt * 16 + lr] = oacc[dt][e] * inv;
  }
}

extern "C" void kernel_launch(void* const* d_in, const int* in_sizes, int n_in,
                              void* d_out, int out_size, void* d_ws, size_t ws_size,
                              hipStream_t stream) {
  const float* Q = (const float*)d_in[0];
  const float* K = (const float*)d_in[1];
  const float* V = (const float*)d_in[2];
  float* O = (float*)d_out;
  dim3 grid(SEQ / QT, NB * NQH);
  gqa_fwd<<<grid, 256, 0, stream>>>(Q, K, V, O);
}